// Round 4
// baseline (199.603 us; speedup 1.0000x reference)
//
#include <hip/hip_runtime.h>
#include <hip/hip_bf16.h>

typedef __bf16 bf16_t;
typedef __attribute__((ext_vector_type(8))) __bf16 bf16x8;
typedef __attribute__((ext_vector_type(4))) float f32x4;

#define MFMA16(a, b, c) __builtin_amdgcn_mfma_f32_16x16x32_bf16((a), (b), (c), 0, 0, 0)

constexpr int NB   = 2;      // batch
constexpr int NH   = 8;      // heads
constexpr int NSEQ = 2048;   // tokens
constexpr int CD   = 512;    // channel dim
constexpr int DH   = 64;     // head dim
constexpr int MTOK = NB * NSEQ;  // 4096

__device__ __forceinline__ bf16_t f2b(float x) { return (bf16_t)x; }

// load 8 consecutive fp32 and convert to a bf16x8 MFMA fragment
__device__ __forceinline__ bf16x8 load8f(const float* __restrict__ p) {
    f32x4 a = *reinterpret_cast<const f32x4*>(p);
    f32x4 b = *reinterpret_cast<const f32x4*>(p + 4);
    bf16x8 r;
    #pragma unroll
    for (int i = 0; i < 4; ++i) { r[i] = (bf16_t)a[i]; r[4 + i] = (bf16_t)b[i]; }
    return r;
}

// ------------------------------------------------------------------
// QKV projection: C = X @ W^T (X [4096,512] fp32, W [512,512] fp32 [out,in])
// Output head-split bf16: [b][h][n][64].  grid (64, 8, 3), block 256 (4 waves).
// ------------------------------------------------------------------
__global__ __launch_bounds__(256) void qkv_proj_kernel(
    const float* __restrict__ Xq, const float* __restrict__ Xk, const float* __restrict__ Xv,
    const float* __restrict__ Wq, const float* __restrict__ Wk, const float* __restrict__ Wv,
    bf16_t* __restrict__ Qp, bf16_t* __restrict__ Kp, bf16_t* __restrict__ Vp)
{
    const int z = blockIdx.z;
    const float* __restrict__ X = (z == 0) ? Xq : (z == 1) ? Xk : Xv;
    const float* __restrict__ W = (z == 0) ? Wq : (z == 1) ? Wk : Wv;
    bf16_t* __restrict__ Out    = (z == 0) ? Qp : (z == 1) ? Kp : Vp;

    const int lane = threadIdx.x & 63;
    const int wid  = threadIdx.x >> 6;
    const int m0 = blockIdx.x * 64 + (wid >> 1) * 32;
    const int n0 = blockIdx.y * 64 + (wid & 1) * 32;

    const int lrow = lane & 15;
    const int lk   = (lane >> 4) * 8;

    f32x4 acc[2][2] = {};
    for (int k0 = 0; k0 < CD; k0 += 32) {
        bf16x8 a0 = load8f(X + (size_t)(m0 + lrow)      * CD + k0 + lk);
        bf16x8 a1 = load8f(X + (size_t)(m0 + 16 + lrow) * CD + k0 + lk);
        bf16x8 b0 = load8f(W + (size_t)(n0 + lrow)      * CD + k0 + lk);
        bf16x8 b1 = load8f(W + (size_t)(n0 + 16 + lrow) * CD + k0 + lk);
        acc[0][0] = MFMA16(a0, b0, acc[0][0]);
        acc[0][1] = MFMA16(a0, b1, acc[0][1]);
        acc[1][0] = MFMA16(a1, b0, acc[1][0]);
        acc[1][1] = MFMA16(a1, b1, acc[1][1]);
    }

    #pragma unroll
    for (int f = 0; f < 2; ++f)
        #pragma unroll
        for (int g = 0; g < 2; ++g)
            #pragma unroll
            for (int j = 0; j < 4; ++j) {
                int row = m0 + f * 16 + (lane >> 4) * 4 + j;   // token index
                int col = n0 + g * 16 + (lane & 15);           // output feature
                int b = row >> 11, n = row & (NSEQ - 1);
                int h = col >> 6,  d = col & (DH - 1);
                Out[(((size_t)(b * NH + h) * NSEQ) + n) * DH + d] = f2b(acc[f][g][j]);
            }
}

// ------------------------------------------------------------------
// Causal flash attention. Qp/Kp/Vp head-split [b][h][n][64] bf16.
// One wave handles a 16-row Q-tile; K-tiles of 32 cols; online softmax.
// Pairing: wave does q-tile p and q-tile 127-p -> 65 iters each, balanced.
// grid (16 bh, 16), block 256 (4 waves).
// ------------------------------------------------------------------
__device__ __forceinline__ void attn_qtile(
    const bf16_t* __restrict__ Q, const bf16_t* __restrict__ K,
    const bf16_t* __restrict__ V, bf16_t* __restrict__ A,
    int qbase, bf16_t (*Pl)[40], int lane)
{
    const int lrow  = lane & 15;
    const int lk    = (lane >> 4) * 8;
    const int jrow0 = (lane >> 4) * 4;

    // Q fragments (contraction d: 0-31 and 32-63)
    bf16x8 aq0 = *reinterpret_cast<const bf16x8*>(Q + (size_t)(qbase + lrow) * DH + lk);
    bf16x8 aq1 = *reinterpret_cast<const bf16x8*>(Q + (size_t)(qbase + lrow) * DH + 32 + lk);

    float m[4], l[4];
    f32x4 O[4] = {};
    #pragma unroll
    for (int j = 0; j < 4; ++j) { m[j] = -1e30f; l[j] = 0.f; }

    const int ntiles = qbase / 32 + 1;
    for (int t = 0; t < ntiles; ++t) {
        const int kb = t * 32;

        // S = (Q K^T) fragments: s[kk] cols kb+kk*16+lrow, rows qbase+jrow0+j
        f32x4 s[2] = {};
        #pragma unroll
        for (int kk = 0; kk < 2; ++kk) {
            bf16x8 bk0 = *reinterpret_cast<const bf16x8*>(K + (size_t)(kb + kk * 16 + lrow) * DH + lk);
            bf16x8 bk1 = *reinterpret_cast<const bf16x8*>(K + (size_t)(kb + kk * 16 + lrow) * DH + 32 + lk);
            s[kk] = MFMA16(aq0, bk0, s[kk]);
            s[kk] = MFMA16(aq1, bk1, s[kk]);
        }

        const bool diag = (t == ntiles - 1);
        #pragma unroll
        for (int kk = 0; kk < 2; ++kk)
            #pragma unroll
            for (int j = 0; j < 4; ++j) {
                float x = s[kk][j] * 0.125f;   // 1/sqrt(64)
                if (diag) {
                    int kg = kb + kk * 16 + lrow;
                    int qg = qbase + jrow0 + j;
                    if (kg > qg) x = -1e30f;
                }
                s[kk][j] = x;
            }

        // row max across 32 cols: register pair + shfl within 16-lane group
        float mx[4], mn[4], al[4], rs[4], p0[4], p1[4];
        #pragma unroll
        for (int j = 0; j < 4; ++j) mx[j] = fmaxf(s[0][j], s[1][j]);
        #pragma unroll
        for (int d = 1; d < 16; d <<= 1)
            #pragma unroll
            for (int j = 0; j < 4; ++j) mx[j] = fmaxf(mx[j], __shfl_xor(mx[j], d));

        #pragma unroll
        for (int j = 0; j < 4; ++j) {
            mn[j] = fmaxf(m[j], mx[j]);
            al[j] = __expf(m[j] - mn[j]);
            p0[j] = __expf(s[0][j] - mn[j]);
            p1[j] = __expf(s[1][j] - mn[j]);
            rs[j] = p0[j] + p1[j];
        }
        #pragma unroll
        for (int d = 1; d < 16; d <<= 1)
            #pragma unroll
            for (int j = 0; j < 4; ++j) rs[j] += __shfl_xor(rs[j], d);
        #pragma unroll
        for (int j = 0; j < 4; ++j) {
            l[j] = l[j] * al[j] + rs[j];
            m[j] = mn[j];
        }
        #pragma unroll
        for (int df = 0; df < 4; ++df)
            #pragma unroll
            for (int j = 0; j < 4; ++j) O[df][j] *= al[j];

        // P -> LDS ([16 q][32 k], padded to 40), then reload as MFMA A-fragment
        #pragma unroll
        for (int j = 0; j < 4; ++j) {
            Pl[jrow0 + j][lrow]      = f2b(p0[j]);
            Pl[jrow0 + j][16 + lrow] = f2b(p1[j]);
        }
        asm volatile("s_waitcnt lgkmcnt(0)" ::: "memory");
        bf16x8 pa = *reinterpret_cast<const bf16x8*>(&Pl[lrow][lk]);

        // O += P @ V  (V fragments: strided column reads, L1/L2-cached)
        #pragma unroll
        for (int df = 0; df < 4; ++df) {
            bf16x8 bv;
            #pragma unroll
            for (int j = 0; j < 8; ++j)
                bv[j] = V[(size_t)(kb + lk + j) * DH + df * 16 + lrow];
            O[df] = MFMA16(pa, bv, O[df]);
        }
    }

    // epilogue: O / l, write merged-head layout A[n][h*64+d]
    #pragma unroll
    for (int df = 0; df < 4; ++df)
        #pragma unroll
        for (int j = 0; j < 4; ++j) {
            float val = O[df][j] / l[j];
            A[(size_t)(qbase + jrow0 + j) * CD + df * 16 + lrow] = f2b(val);
        }
}

__global__ __launch_bounds__(256) void attn_kernel(
    const bf16_t* __restrict__ Qp, const bf16_t* __restrict__ Kp,
    const bf16_t* __restrict__ Vp, bf16_t* __restrict__ Aout)
{
    __shared__ bf16_t Pl[4][16][40];
    const int lane = threadIdx.x & 63;
    const int wid  = threadIdx.x >> 6;
    const int bh = blockIdx.x;           // 0..15
    const int b = bh >> 3, h = bh & 7;
    const int p = blockIdx.y * 4 + wid;  // 0..63

    const bf16_t* Q = Qp + (size_t)bh * NSEQ * DH;
    const bf16_t* K = Kp + (size_t)bh * NSEQ * DH;
    const bf16_t* V = Vp + (size_t)bh * NSEQ * DH;
    bf16_t* A = Aout + (size_t)b * NSEQ * CD + h * DH;

    attn_qtile(Q, K, V, A, 16 * p,         Pl[wid], lane);
    attn_qtile(Q, K, V, A, 16 * (127 - p), Pl[wid], lane);
}

// ------------------------------------------------------------------
// Output projection: out = A @ Wo^T + bo.  A [4096,512] bf16,
// Wo [512,512] fp32, bo fp32, out fp32.  grid (64, 8), block 256.
// ------------------------------------------------------------------
__global__ __launch_bounds__(256) void out_proj_kernel(
    const bf16_t* __restrict__ A, const float* __restrict__ Wo,
    const float* __restrict__ bo, float* __restrict__ Out)
{
    const int lane = threadIdx.x & 63;
    const int wid  = threadIdx.x >> 6;
    const int m0 = blockIdx.x * 64 + (wid >> 1) * 32;
    const int n0 = blockIdx.y * 64 + (wid & 1) * 32;

    const int lrow = lane & 15;
    const int lk   = (lane >> 4) * 8;

    f32x4 acc[2][2] = {};
    for (int k0 = 0; k0 < CD; k0 += 32) {
        bf16x8 a0 = *reinterpret_cast<const bf16x8*>(A + (size_t)(m0 + lrow)      * CD + k0 + lk);
        bf16x8 a1 = *reinterpret_cast<const bf16x8*>(A + (size_t)(m0 + 16 + lrow) * CD + k0 + lk);
        bf16x8 b0 = load8f(Wo + (size_t)(n0 + lrow)      * CD + k0 + lk);
        bf16x8 b1 = load8f(Wo + (size_t)(n0 + 16 + lrow) * CD + k0 + lk);
        acc[0][0] = MFMA16(a0, b0, acc[0][0]);
        acc[0][1] = MFMA16(a0, b1, acc[0][1]);
        acc[1][0] = MFMA16(a1, b0, acc[1][0]);
        acc[1][1] = MFMA16(a1, b1, acc[1][1]);
    }

    #pragma unroll
    for (int f = 0; f < 2; ++f)
        #pragma unroll
        for (int g = 0; g < 2; ++g)
            #pragma unroll
            for (int j = 0; j < 4; ++j) {
                int row = m0 + f * 16 + (lane >> 4) * 4 + j;
                int col = n0 + g * 16 + (lane & 15);
                Out[(size_t)row * CD + col] = acc[f][g][j] + bo[col];
            }
}

// simple d2d copy, 16 B per thread
__global__ __launch_bounds__(256) void copy16_kernel(
    const f32x4* __restrict__ src, f32x4* __restrict__ dst, int n16)
{
    int i = blockIdx.x * 256 + threadIdx.x;
    if (i < n16) dst[i] = src[i];
}

// ------------------------------------------------------------------
extern "C" void kernel_launch(void* const* d_in, const int* in_sizes, int n_in,
                              void* d_out, int out_size, void* d_ws, size_t ws_size,
                              hipStream_t stream)
{
    const float* q  = (const float*)d_in[0];
    const float* k  = (const float*)d_in[1];
    const float* v  = (const float*)d_in[2];
    const float* Wq = (const float*)d_in[3];
    const float* Wk = (const float*)d_in[4];
    const float* Wv = (const float*)d_in[5];
    const float* Wo = (const float*)d_in[6];
    const float* bo = (const float*)d_in[7];

    const size_t proj_elems = (size_t)MTOK * CD;        // 2,097,152 bf16 = 4 MB
    const size_t proj_bytes = proj_elems * sizeof(bf16_t);

    if (ws_size >= 4 * proj_bytes) {
        // --- Path A: everything fits in workspace (16 MB) ---
        bf16_t* Qp   = (bf16_t*)d_ws;
        bf16_t* Kp   = Qp + proj_elems;
        bf16_t* Vp   = Kp + proj_elems;
        bf16_t* Aout = Vp + proj_elems;

        qkv_proj_kernel<<<dim3(MTOK / 64, CD / 64, 3), 256, 0, stream>>>(
            q, k, v, Wq, Wk, Wv, Qp, Kp, Vp);
        attn_kernel<<<dim3(NB * NH, 16), 256, 0, stream>>>(Qp, Kp, Vp, Aout);
        out_proj_kernel<<<dim3(MTOK / 64, CD / 64), 256, 0, stream>>>(
            Aout, Wo, bo, (float*)d_out);
    } else {
        // --- Path B: ws has only ~8 MB; use d_out (8 MB fp32) as scratch ---
        // Q-packed bf16 -> d_out[0:4MB); K,V -> ws[0:8MB);
        // attn writes A-bf16 -> d_out[4:8MB); copy A -> ws[0:4MB) (K/V dead);
        // out_proj reads A from ws, rewrites all of d_out as fp32.
        bf16_t* Qp   = (bf16_t*)d_out;
        bf16_t* Kp   = (bf16_t*)d_ws;
        bf16_t* Vp   = Kp + proj_elems;
        bf16_t* Atmp = Qp + proj_elems;          // d_out bytes [4MB, 8MB)
        bf16_t* Afin = (bf16_t*)d_ws;            // reuse K region after attn

        qkv_proj_kernel<<<dim3(MTOK / 64, CD / 64, 3), 256, 0, stream>>>(
            q, k, v, Wq, Wk, Wv, Qp, Kp, Vp);
        attn_kernel<<<dim3(NB * NH, 16), 256, 0, stream>>>(Qp, Kp, Vp, Atmp);
        const int n16 = (int)(proj_bytes / 16);  // 262144
        copy16_kernel<<<dim3(n16 / 256), 256, 0, stream>>>(
            (const f32x4*)Atmp, (f32x4*)Afin, n16);
        out_proj_kernel<<<dim3(MTOK / 64, CD / 64), 256, 0, stream>>>(
            Afin, Wo, bo, (float*)d_out);
    }
}

// Round 5
// 108.814 us; speedup vs baseline: 1.8344x; 1.8344x over previous
//
#include <hip/hip_runtime.h>
#include <hip/hip_bf16.h>

typedef __bf16 bf16_t;
typedef __attribute__((ext_vector_type(4))) __bf16 bf16x4;
typedef __attribute__((ext_vector_type(8))) __bf16 bf16x8;
typedef __attribute__((ext_vector_type(4))) float f32x4;

#define MFMA16(a, b, c) __builtin_amdgcn_mfma_f32_16x16x32_bf16((a), (b), (c), 0, 0, 0)

constexpr int NB   = 2;      // batch
constexpr int NH   = 8;      // heads
constexpr int NSEQ = 2048;   // tokens
constexpr int CD   = 512;    // channel dim
constexpr int DH   = 64;     // head dim
constexpr int MTOK = NB * NSEQ;  // 4096

__device__ __forceinline__ bf16_t f2b(float x) { return (bf16_t)x; }

// ------------------------------------------------------------------
// QKV projection, LDS-staged: C = X @ W^T.
// X [4096,512] fp32, W [512,512] fp32 ([out,in]).
// Q,K outputs head-split bf16 [b][h][n][64]; V output TRANSPOSED
// bf16 [b][h][64][n] for vectorized PV loads in attention.
// grid (64, 8, 3), block 256 (4 waves, 2x2 of 32x32 tiles).
// ------------------------------------------------------------------
__global__ __launch_bounds__(256) void qkv_proj_kernel(
    const float* __restrict__ Xq, const float* __restrict__ Xk, const float* __restrict__ Xv,
    const float* __restrict__ Wq, const float* __restrict__ Wk, const float* __restrict__ Wv,
    bf16_t* __restrict__ Qp, bf16_t* __restrict__ Kp, bf16_t* __restrict__ Vt)
{
    __shared__ bf16_t Xs[64][72];   // stride 36 words -> 2-way bank alias (free)
    __shared__ bf16_t Ws[64][72];

    const int z = blockIdx.z;
    const float* __restrict__ X = (z == 0) ? Xq : (z == 1) ? Xk : Xv;
    const float* __restrict__ W = (z == 0) ? Wq : (z == 1) ? Wk : Wv;
    bf16_t* __restrict__ Out    = (z == 0) ? Qp : (z == 1) ? Kp : Vt;

    const int tid  = threadIdx.x;
    const int lane = tid & 63;
    const int wid  = tid >> 6;
    const int lrow = lane & 15;
    const int lk   = (lane >> 4) * 8;
    const int m0w  = (wid >> 1) * 32;
    const int n0w  = (wid & 1) * 32;
    const int bm   = blockIdx.x * 64;
    const int bn   = blockIdx.y * 64;

    const int srow = tid >> 4;        // 0..15
    const int sc4  = (tid & 15) * 4;  // 0..60

    f32x4 acc[2][2] = {};
    for (int k0 = 0; k0 < CD; k0 += 64) {
        // stage 64x64 tiles of X and W, fp32 -> bf16
        #pragma unroll
        for (int rr = 0; rr < 4; ++rr) {
            int r = rr * 16 + srow;
            f32x4 xv = *reinterpret_cast<const f32x4*>(X + (size_t)(bm + r) * CD + k0 + sc4);
            f32x4 wv = *reinterpret_cast<const f32x4*>(W + (size_t)(bn + r) * CD + k0 + sc4);
            bf16x4 xb, wb;
            #pragma unroll
            for (int c = 0; c < 4; ++c) { xb[c] = f2b(xv[c]); wb[c] = f2b(wv[c]); }
            *reinterpret_cast<bf16x4*>(&Xs[r][sc4]) = xb;
            *reinterpret_cast<bf16x4*>(&Ws[r][sc4]) = wb;
        }
        __syncthreads();
        #pragma unroll
        for (int kk = 0; kk < 2; ++kk) {
            int o = kk * 32 + lk;
            bf16x8 a0 = *reinterpret_cast<const bf16x8*>(&Xs[m0w + lrow][o]);
            bf16x8 a1 = *reinterpret_cast<const bf16x8*>(&Xs[m0w + 16 + lrow][o]);
            bf16x8 b0 = *reinterpret_cast<const bf16x8*>(&Ws[n0w + lrow][o]);
            bf16x8 b1 = *reinterpret_cast<const bf16x8*>(&Ws[n0w + 16 + lrow][o]);
            acc[0][0] = MFMA16(a0, b0, acc[0][0]);
            acc[0][1] = MFMA16(a0, b1, acc[0][1]);
            acc[1][0] = MFMA16(a1, b0, acc[1][0]);
            acc[1][1] = MFMA16(a1, b1, acc[1][1]);
        }
        __syncthreads();
    }

    // epilogue
    if (z == 2) {
        // V transposed: Vt[((b*NH+h)*DH + d)*NSEQ + n], pack 4 consecutive n
        #pragma unroll
        for (int f = 0; f < 2; ++f)
            #pragma unroll
            for (int g = 0; g < 2; ++g) {
                int rowb = bm + m0w + f * 16 + (lane >> 4) * 4;  // 4-aligned
                int col  = bn + n0w + g * 16 + lrow;
                int b = rowb >> 11, n = rowb & (NSEQ - 1);
                int h = col >> 6,  d = col & (DH - 1);
                bf16x4 pk;
                #pragma unroll
                for (int j = 0; j < 4; ++j) pk[j] = f2b(acc[f][g][j]);
                *reinterpret_cast<bf16x4*>(Out + (((size_t)(b * NH + h) * DH) + d) * NSEQ + n) = pk;
            }
    } else {
        #pragma unroll
        for (int f = 0; f < 2; ++f)
            #pragma unroll
            for (int g = 0; g < 2; ++g)
                #pragma unroll
                for (int j = 0; j < 4; ++j) {
                    int row = bm + m0w + f * 16 + (lane >> 4) * 4 + j;
                    int col = bn + n0w + g * 16 + lrow;
                    int b = row >> 11, n = row & (NSEQ - 1);
                    int h = col >> 6,  d = col & (DH - 1);
                    Out[(((size_t)(b * NH + h) * NSEQ) + n) * DH + d] = f2b(acc[f][g][j]);
                }
    }
}

// ------------------------------------------------------------------
// Causal flash attention, split-KV x4.
// One block = one 16-row Q-tile; 4 waves each take K-tiles t = w, w+4, ...
// Partial (m, l, O) merged through LDS. V is transposed [bh][64][NSEQ].
// grid (16 bh, 128 qtiles, descending work), block 256.
// ------------------------------------------------------------------
__global__ __launch_bounds__(256) void attn_kernel(
    const bf16_t* __restrict__ Qp, const bf16_t* __restrict__ Kp,
    const bf16_t* __restrict__ Vt, bf16_t* __restrict__ Aout)
{
    __shared__ float  sO[4][16][64];
    __shared__ float  sm[4][16];
    __shared__ float  sl[4][16];
    __shared__ bf16_t Pl[4][16][40];

    const int lane = threadIdx.x & 63;
    const int w    = threadIdx.x >> 6;
    const int bh = blockIdx.x;           // 0..15
    const int b = bh >> 3, h = bh & 7;
    const int p = 127 - blockIdx.y;      // heavy blocks first
    const int qbase = p * 16;

    const bf16_t* Q = Qp + (size_t)bh * NSEQ * DH;
    const bf16_t* K = Kp + (size_t)bh * NSEQ * DH;
    const bf16_t* V = Vt + (size_t)bh * DH * NSEQ;

    const int lrow  = lane & 15;
    const int lk    = (lane >> 4) * 8;
    const int jrow0 = (lane >> 4) * 4;

    // Q fragments, pre-scaled by 1/sqrt(64)=0.125 (exact in bf16)
    bf16x8 aq0, aq1;
    {
        bf16x8 t0 = *reinterpret_cast<const bf16x8*>(Q + (size_t)(qbase + lrow) * DH + lk);
        bf16x8 t1 = *reinterpret_cast<const bf16x8*>(Q + (size_t)(qbase + lrow) * DH + 32 + lk);
        #pragma unroll
        for (int i = 0; i < 8; ++i) {
            aq0[i] = f2b((float)t0[i] * 0.125f);
            aq1[i] = f2b((float)t1[i] * 0.125f);
        }
    }

    float m[4], l[4];
    f32x4 O[4] = {};
    #pragma unroll
    for (int j = 0; j < 4; ++j) { m[j] = -1e30f; l[j] = 0.f; }

    const int T = (16 * p + 47) >> 5;   // #32-wide K-tiles covering keys [0, 16p+16)
    for (int t = w; t < T; t += 4) {
        const int kb = t * 32;

        f32x4 s[2] = {};
        #pragma unroll
        for (int kk = 0; kk < 2; ++kk) {
            bf16x8 bk0 = *reinterpret_cast<const bf16x8*>(K + (size_t)(kb + kk * 16 + lrow) * DH + lk);
            bf16x8 bk1 = *reinterpret_cast<const bf16x8*>(K + (size_t)(kb + kk * 16 + lrow) * DH + 32 + lk);
            s[kk] = MFMA16(aq0, bk0, s[kk]);
            s[kk] = MFMA16(aq1, bk1, s[kk]);
        }

        if (kb + 31 > qbase) {   // only the diagonal tile needs masking
            #pragma unroll
            for (int kk = 0; kk < 2; ++kk)
                #pragma unroll
                for (int j = 0; j < 4; ++j) {
                    int kg = kb + kk * 16 + lrow;
                    int qg = qbase + jrow0 + j;
                    if (kg > qg) s[kk][j] = -1e30f;
                }
        }

        // online softmax: row reduce over 32 cols (reg pair + 16-lane shfl tree)
        float mx[4], mn[4], al[4], rs[4], p0[4], p1[4];
        #pragma unroll
        for (int j = 0; j < 4; ++j) mx[j] = fmaxf(s[0][j], s[1][j]);
        #pragma unroll
        for (int d = 1; d < 16; d <<= 1)
            #pragma unroll
            for (int j = 0; j < 4; ++j) mx[j] = fmaxf(mx[j], __shfl_xor(mx[j], d));

        #pragma unroll
        for (int j = 0; j < 4; ++j) {
            mn[j] = fmaxf(m[j], mx[j]);
            al[j] = __expf(m[j] - mn[j]);
            p0[j] = __expf(s[0][j] - mn[j]);
            p1[j] = __expf(s[1][j] - mn[j]);
            rs[j] = p0[j] + p1[j];
        }
        #pragma unroll
        for (int d = 1; d < 16; d <<= 1)
            #pragma unroll
            for (int j = 0; j < 4; ++j) rs[j] += __shfl_xor(rs[j], d);
        #pragma unroll
        for (int j = 0; j < 4; ++j) {
            l[j] = l[j] * al[j] + rs[j];
            m[j] = mn[j];
        }
        #pragma unroll
        for (int df = 0; df < 4; ++df)
            #pragma unroll
            for (int j = 0; j < 4; ++j) O[df][j] *= al[j];

        // P -> LDS bounce into MFMA A-fragment layout
        #pragma unroll
        for (int j = 0; j < 4; ++j) {
            Pl[w][jrow0 + j][lrow]      = f2b(p0[j]);
            Pl[w][jrow0 + j][16 + lrow] = f2b(p1[j]);
        }
        asm volatile("s_waitcnt lgkmcnt(0)" ::: "memory");
        bf16x8 pa = *reinterpret_cast<const bf16x8*>(&Pl[w][lrow][lk]);

        // O += P @ V : vectorized 16B loads from transposed V
        #pragma unroll
        for (int df = 0; df < 4; ++df) {
            bf16x8 bv = *reinterpret_cast<const bf16x8*>(V + (size_t)(df * 16 + lrow) * NSEQ + kb + lk);
            O[df] = MFMA16(pa, bv, O[df]);
        }
    }

    // dump per-wave partials
    #pragma unroll
    for (int df = 0; df < 4; ++df)
        #pragma unroll
        for (int j = 0; j < 4; ++j)
            sO[w][jrow0 + j][df * 16 + lrow] = O[df][j];
    if (lrow == 0) {
        #pragma unroll
        for (int j = 0; j < 4; ++j) { sm[w][jrow0 + j] = m[j]; sl[w][jrow0 + j] = l[j]; }
    }
    __syncthreads();

    // combine 4 partials: thread -> (row, 4 cols)
    const int row = threadIdx.x >> 4;
    const int c0  = (threadIdx.x & 15) * 4;
    float mstar = fmaxf(fmaxf(sm[0][row], sm[1][row]), fmaxf(sm[2][row], sm[3][row]));
    f32x4 accv = {};
    float lstar = 0.f;
    #pragma unroll
    for (int w2 = 0; w2 < 4; ++w2) {
        float sc = __expf(sm[w2][row] - mstar);
        lstar += sl[w2][row] * sc;
        f32x4 ov = *reinterpret_cast<const f32x4*>(&sO[w2][row][c0]);
        accv += ov * sc;
    }
    float inv = 1.f / lstar;
    bf16x4 pk;
    #pragma unroll
    for (int c = 0; c < 4; ++c) pk[c] = f2b(accv[c] * inv);
    *reinterpret_cast<bf16x4*>(Aout + ((size_t)b * NSEQ + qbase + row) * CD + h * DH + c0) = pk;
}

// ------------------------------------------------------------------
// Output projection, LDS-staged: out = A @ Wo^T + bo.
// A [4096,512] bf16, Wo [512,512] fp32, out fp32. grid (64,8), block 256.
// ------------------------------------------------------------------
__global__ __launch_bounds__(256) void out_proj_kernel(
    const bf16_t* __restrict__ A, const float* __restrict__ Wo,
    const float* __restrict__ bo, float* __restrict__ Out)
{
    __shared__ bf16_t As[64][72];
    __shared__ bf16_t Ws[64][72];

    const int tid  = threadIdx.x;
    const int lane = tid & 63;
    const int wid  = tid >> 6;
    const int lrow = lane & 15;
    const int lk   = (lane >> 4) * 8;
    const int m0w  = (wid >> 1) * 32;
    const int n0w  = (wid & 1) * 32;
    const int bm   = blockIdx.x * 64;
    const int bn   = blockIdx.y * 64;

    const int srow = tid >> 4;
    const int sc4  = (tid & 15) * 4;

    f32x4 acc[2][2] = {};
    for (int k0 = 0; k0 < CD; k0 += 64) {
        #pragma unroll
        for (int rr = 0; rr < 4; ++rr) {
            int r = rr * 16 + srow;
            bf16x4 ab = *reinterpret_cast<const bf16x4*>(A + (size_t)(bm + r) * CD + k0 + sc4);
            f32x4  wv = *reinterpret_cast<const f32x4*>(Wo + (size_t)(bn + r) * CD + k0 + sc4);
            bf16x4 wb;
            #pragma unroll
            for (int c = 0; c < 4; ++c) wb[c] = f2b(wv[c]);
            *reinterpret_cast<bf16x4*>(&As[r][sc4]) = ab;
            *reinterpret_cast<bf16x4*>(&Ws[r][sc4]) = wb;
        }
        __syncthreads();
        #pragma unroll
        for (int kk = 0; kk < 2; ++kk) {
            int o = kk * 32 + lk;
            bf16x8 a0 = *reinterpret_cast<const bf16x8*>(&As[m0w + lrow][o]);
            bf16x8 a1 = *reinterpret_cast<const bf16x8*>(&As[m0w + 16 + lrow][o]);
            bf16x8 b0 = *reinterpret_cast<const bf16x8*>(&Ws[n0w + lrow][o]);
            bf16x8 b1 = *reinterpret_cast<const bf16x8*>(&Ws[n0w + 16 + lrow][o]);
            acc[0][0] = MFMA16(a0, b0, acc[0][0]);
            acc[0][1] = MFMA16(a0, b1, acc[0][1]);
            acc[1][0] = MFMA16(a1, b0, acc[1][0]);
            acc[1][1] = MFMA16(a1, b1, acc[1][1]);
        }
        __syncthreads();
    }

    #pragma unroll
    for (int f = 0; f < 2; ++f)
        #pragma unroll
        for (int g = 0; g < 2; ++g)
            #pragma unroll
            for (int j = 0; j < 4; ++j) {
                int row = bm + m0w + f * 16 + (lane >> 4) * 4 + j;
                int col = bn + n0w + g * 16 + lrow;
                Out[(size_t)row * CD + col] = acc[f][g][j] + bo[col];
            }
}

// simple d2d copy, 16 B per thread
__global__ __launch_bounds__(256) void copy16_kernel(
    const f32x4* __restrict__ src, f32x4* __restrict__ dst, int n16)
{
    int i = blockIdx.x * 256 + threadIdx.x;
    if (i < n16) dst[i] = src[i];
}

// ------------------------------------------------------------------
extern "C" void kernel_launch(void* const* d_in, const int* in_sizes, int n_in,
                              void* d_out, int out_size, void* d_ws, size_t ws_size,
                              hipStream_t stream)
{
    const float* q  = (const float*)d_in[0];
    const float* k  = (const float*)d_in[1];
    const float* v  = (const float*)d_in[2];
    const float* Wq = (const float*)d_in[3];
    const float* Wk = (const float*)d_in[4];
    const float* Wv = (const float*)d_in[5];
    const float* Wo = (const float*)d_in[6];
    const float* bo = (const float*)d_in[7];

    const size_t proj_elems = (size_t)MTOK * CD;        // 2,097,152 bf16 = 4 MB
    const size_t proj_bytes = proj_elems * sizeof(bf16_t);

    if (ws_size >= 4 * proj_bytes) {
        // --- Path A: everything fits in workspace (16 MB) ---
        bf16_t* Qp   = (bf16_t*)d_ws;
        bf16_t* Kp   = Qp + proj_elems;
        bf16_t* Vt   = Kp + proj_elems;
        bf16_t* Aout = Vt + proj_elems;

        qkv_proj_kernel<<<dim3(MTOK / 64, CD / 64, 3), 256, 0, stream>>>(
            q, k, v, Wq, Wk, Wv, Qp, Kp, Vt);
        attn_kernel<<<dim3(NB * NH, 128), 256, 0, stream>>>(Qp, Kp, Vt, Aout);
        out_proj_kernel<<<dim3(MTOK / 64, CD / 64), 256, 0, stream>>>(
            Aout, Wo, bo, (float*)d_out);
    } else {
        // --- Path B: ws has only ~8 MB; use d_out (8 MB fp32) as scratch ---
        bf16_t* Qp   = (bf16_t*)d_out;
        bf16_t* Kp   = (bf16_t*)d_ws;
        bf16_t* Vt   = Kp + proj_elems;
        bf16_t* Atmp = Qp + proj_elems;          // d_out bytes [4MB, 8MB)
        bf16_t* Afin = (bf16_t*)d_ws;            // reuse K region after attn

        qkv_proj_kernel<<<dim3(MTOK / 64, CD / 64, 3), 256, 0, stream>>>(
            q, k, v, Wq, Wk, Wv, Qp, Kp, Vt);
        attn_kernel<<<dim3(NB * NH, 128), 256, 0, stream>>>(Qp, Kp, Vt, Atmp);
        const int n16 = (int)(proj_bytes / 16);  // 262144
        copy16_kernel<<<dim3(n16 / 256), 256, 0, stream>>>(
            (const f32x4*)Atmp, (f32x4*)Afin, n16);
        out_proj_kernel<<<dim3(MTOK / 64, CD / 64), 256, 0, stream>>>(
            Afin, Wo, bo, (float*)d_out);
    }
}

// Round 6
// 77.276 us; speedup vs baseline: 2.5830x; 1.4081x over previous
//
#include <hip/hip_runtime.h>
#include <hip/hip_bf16.h>

typedef __bf16 bf16_t;
typedef __attribute__((ext_vector_type(4))) __bf16 bf16x4;
typedef __attribute__((ext_vector_type(8))) __bf16 bf16x8;
typedef __attribute__((ext_vector_type(4))) float f32x4;

#define MFMA16(a, b, c) __builtin_amdgcn_mfma_f32_16x16x32_bf16((a), (b), (c), 0, 0, 0)

constexpr int NB   = 2;      // batch
constexpr int NH   = 8;      // heads
constexpr int NSEQ = 2048;   // tokens
constexpr int CD   = 512;    // channel dim
constexpr int DH   = 64;     // head dim
constexpr int MTOK = NB * NSEQ;  // 4096

__device__ __forceinline__ bf16_t f2b(float x) { return (bf16_t)x; }

// ------------------------------------------------------------------
// QKV projection, LDS-staged: C = X @ W^T.
// X [4096,512] fp32, W [512,512] fp32 ([out,in]).
// Q,K outputs head-split bf16 [b][h][n][64]; V output TRANSPOSED
// bf16 [b][h][64][n] for vectorized PV loads in attention.
// grid (64, 8, 3), block 256 (4 waves, 2x2 of 32x32 tiles).
// ------------------------------------------------------------------
__global__ __launch_bounds__(256) void qkv_proj_kernel(
    const float* __restrict__ Xq, const float* __restrict__ Xk, const float* __restrict__ Xv,
    const float* __restrict__ Wq, const float* __restrict__ Wk, const float* __restrict__ Wv,
    bf16_t* __restrict__ Qp, bf16_t* __restrict__ Kp, bf16_t* __restrict__ Vt)
{
    __shared__ bf16_t Xs[64][72];   // stride 36 words -> 2-way bank alias (free)
    __shared__ bf16_t Ws[64][72];

    const int z = blockIdx.z;
    const float* __restrict__ X = (z == 0) ? Xq : (z == 1) ? Xk : Xv;
    const float* __restrict__ W = (z == 0) ? Wq : (z == 1) ? Wk : Wv;
    bf16_t* __restrict__ Out    = (z == 0) ? Qp : (z == 1) ? Kp : Vt;

    const int tid  = threadIdx.x;
    const int lane = tid & 63;
    const int wid  = tid >> 6;
    const int lrow = lane & 15;
    const int lk   = (lane >> 4) * 8;
    const int m0w  = (wid >> 1) * 32;
    const int n0w  = (wid & 1) * 32;
    const int bm   = blockIdx.x * 64;
    const int bn   = blockIdx.y * 64;

    const int srow = tid >> 4;        // 0..15
    const int sc4  = (tid & 15) * 4;  // 0..60

    f32x4 acc[2][2] = {};
    for (int k0 = 0; k0 < CD; k0 += 64) {
        #pragma unroll
        for (int rr = 0; rr < 4; ++rr) {
            int r = rr * 16 + srow;
            f32x4 xv = *reinterpret_cast<const f32x4*>(X + (size_t)(bm + r) * CD + k0 + sc4);
            f32x4 wv = *reinterpret_cast<const f32x4*>(W + (size_t)(bn + r) * CD + k0 + sc4);
            bf16x4 xb, wb;
            #pragma unroll
            for (int c = 0; c < 4; ++c) { xb[c] = f2b(xv[c]); wb[c] = f2b(wv[c]); }
            *reinterpret_cast<bf16x4*>(&Xs[r][sc4]) = xb;
            *reinterpret_cast<bf16x4*>(&Ws[r][sc4]) = wb;
        }
        __syncthreads();
        #pragma unroll
        for (int kk = 0; kk < 2; ++kk) {
            int o = kk * 32 + lk;
            bf16x8 a0 = *reinterpret_cast<const bf16x8*>(&Xs[m0w + lrow][o]);
            bf16x8 a1 = *reinterpret_cast<const bf16x8*>(&Xs[m0w + 16 + lrow][o]);
            bf16x8 b0 = *reinterpret_cast<const bf16x8*>(&Ws[n0w + lrow][o]);
            bf16x8 b1 = *reinterpret_cast<const bf16x8*>(&Ws[n0w + 16 + lrow][o]);
            acc[0][0] = MFMA16(a0, b0, acc[0][0]);
            acc[0][1] = MFMA16(a0, b1, acc[0][1]);
            acc[1][0] = MFMA16(a1, b0, acc[1][0]);
            acc[1][1] = MFMA16(a1, b1, acc[1][1]);
        }
        __syncthreads();
    }

    if (z == 2) {
        // V transposed: Vt[((b*NH+h)*DH + d)*NSEQ + n], pack 4 consecutive n
        #pragma unroll
        for (int f = 0; f < 2; ++f)
            #pragma unroll
            for (int g = 0; g < 2; ++g) {
                int rowb = bm + m0w + f * 16 + (lane >> 4) * 4;  // 4-aligned
                int col  = bn + n0w + g * 16 + lrow;
                int b = rowb >> 11, n = rowb & (NSEQ - 1);
                int h = col >> 6,  d = col & (DH - 1);
                bf16x4 pk;
                #pragma unroll
                for (int j = 0; j < 4; ++j) pk[j] = f2b(acc[f][g][j]);
                *reinterpret_cast<bf16x4*>(Out + (((size_t)(b * NH + h) * DH) + d) * NSEQ + n) = pk;
            }
    } else {
        #pragma unroll
        for (int f = 0; f < 2; ++f)
            #pragma unroll
            for (int g = 0; g < 2; ++g)
                #pragma unroll
                for (int j = 0; j < 4; ++j) {
                    int row = bm + m0w + f * 16 + (lane >> 4) * 4 + j;
                    int col = bn + n0w + g * 16 + lrow;
                    int b = row >> 11, n = row & (NSEQ - 1);
                    int h = col >> 6,  d = col & (DH - 1);
                    Out[(((size_t)(b * NH + h) * NSEQ) + n) * DH + d] = f2b(acc[f][g][j]);
                }
    }
}

// ------------------------------------------------------------------
// Causal flash attention, split-KV x4, swapped QK^T.
// Block = 4 waves; each wave owns the SAME 32 Q rows and K-tiles
// t = w, w+4, ... (32 keys each). QK^T computed as mfma(K, Q) so the
// P-row lives at q = lane&15: row-reduce = 7 in-reg ops + 2 shfl.
// Per-wave LDS region (8 KB) is P-bounce during the loop, fp32
// O-partials at merge. grid (16 bh, 64 qblocks heavy-first), block 256.
// ------------------------------------------------------------------
__global__ __launch_bounds__(256) void attn_kernel(
    const bf16_t* __restrict__ Qp, const bf16_t* __restrict__ Kp,
    const bf16_t* __restrict__ Vt, bf16_t* __restrict__ Aout)
{
    __shared__ __align__(16) char wreg[4][8192];   // per-wave: Pl[32][40]+sAl[32] | sO[32][64]
    __shared__ float sm[4][32];
    __shared__ float sl[4][32];

    const int tid  = threadIdx.x;
    const int lane = tid & 63;
    const int w    = tid >> 6;
    const int r    = lane & 15;        // q-col (QK^T) / d-col (PV)
    const int g    = lane >> 4;        // 0..3
    const int bh = blockIdx.x;
    const int b = bh >> 3, h = bh & 7;
    const int p = 63 - blockIdx.y;     // heavy q-blocks first
    const int qb = p * 32;

    const bf16_t* Q = Qp + (size_t)bh * NSEQ * DH;
    const bf16_t* K = Kp + (size_t)bh * NSEQ * DH;
    const bf16_t* V = Vt + (size_t)bh * DH * NSEQ;

    bf16_t* Pl  = (bf16_t*)wreg[w];            // [32][40]
    float*  sAl = (float*)(wreg[w] + 2560);    // [32]

    // Q fragments (B-operand layout == old A layout), pre-scaled by 1/8
    bf16x8 qf[2][2];
    #pragma unroll
    for (int f = 0; f < 2; ++f)
        #pragma unroll
        for (int dh = 0; dh < 2; ++dh) {
            bf16x8 t = *reinterpret_cast<const bf16x8*>(
                Q + (size_t)(qb + f * 16 + r) * DH + dh * 32 + g * 8);
            #pragma unroll
            for (int i = 0; i < 8; ++i) qf[f][dh][i] = f2b((float)t[i] * 0.125f);
        }

    float m0 = -1e30f, m1 = -1e30f, l0 = 0.f, l1 = 0.f;
    f32x4 O[2][4] = {};

    const int T = p + 1;
    for (int t = w; t < T; t += 4) {
        const int kb = t * 32;

        // V fragments (independent -> issue early)
        bf16x8 bv[4];
        #pragma unroll
        for (int df = 0; df < 4; ++df)
            bv[df] = *reinterpret_cast<const bf16x8*>(V + (size_t)(df * 16 + r) * NSEQ + kb + g * 8);

        // swapped QK^T: s[f][kk][j] = S[k = kb+kk*16+4g+j][q = qb+f*16+r]
        f32x4 s[2][2] = {};
        #pragma unroll
        for (int kk = 0; kk < 2; ++kk) {
            bf16x8 k0 = *reinterpret_cast<const bf16x8*>(K + (size_t)(kb + kk * 16 + r) * DH + g * 8);
            bf16x8 k1 = *reinterpret_cast<const bf16x8*>(K + (size_t)(kb + kk * 16 + r) * DH + 32 + g * 8);
            #pragma unroll
            for (int f = 0; f < 2; ++f) {
                s[f][kk] = MFMA16(k0, qf[f][0], s[f][kk]);
                s[f][kk] = MFMA16(k1, qf[f][1], s[f][kk]);
            }
        }

        if (kb + 31 > qb) {   // only the diagonal tile masks
            #pragma unroll
            for (int f = 0; f < 2; ++f)
                #pragma unroll
                for (int kk = 0; kk < 2; ++kk)
                    #pragma unroll
                    for (int j = 0; j < 4; ++j) {
                        int kg = kb + kk * 16 + g * 4 + j;
                        int qg = qb + f * 16 + r;
                        if (kg > qg) s[f][kk][j] = -1e30f;
                    }
        }

        // row max: 7 in-reg fmax + 2 shfl per fragment (independent chains)
        float mx0 = fmaxf(fmaxf(fmaxf(s[0][0][0], s[0][0][1]), fmaxf(s[0][0][2], s[0][0][3])),
                          fmaxf(fmaxf(s[0][1][0], s[0][1][1]), fmaxf(s[0][1][2], s[0][1][3])));
        float mx1 = fmaxf(fmaxf(fmaxf(s[1][0][0], s[1][0][1]), fmaxf(s[1][0][2], s[1][0][3])),
                          fmaxf(fmaxf(s[1][1][0], s[1][1][1]), fmaxf(s[1][1][2], s[1][1][3])));
        mx0 = fmaxf(mx0, __shfl_xor(mx0, 16));
        mx1 = fmaxf(mx1, __shfl_xor(mx1, 16));
        mx0 = fmaxf(mx0, __shfl_xor(mx0, 32));
        mx1 = fmaxf(mx1, __shfl_xor(mx1, 32));

        float mn0 = fmaxf(m0, mx0), mn1 = fmaxf(m1, mx1);
        float al0 = __expf(m0 - mn0), al1 = __expf(m1 - mn1);
        m0 = mn0; m1 = mn1;

        float rs0 = 0.f, rs1 = 0.f;
        #pragma unroll
        for (int kk = 0; kk < 2; ++kk)
            #pragma unroll
            for (int j = 0; j < 4; ++j) {
                float e0 = __expf(s[0][kk][j] - mn0);
                float e1 = __expf(s[1][kk][j] - mn1);
                s[0][kk][j] = e0; rs0 += e0;
                s[1][kk][j] = e1; rs1 += e1;
            }
        rs0 += __shfl_xor(rs0, 16);
        rs1 += __shfl_xor(rs1, 16);
        rs0 += __shfl_xor(rs0, 32);
        rs1 += __shfl_xor(rs1, 32);
        l0 = l0 * al0 + rs0;
        l1 = l1 * al1 + rs1;

        // P -> LDS (per-wave region), al -> LDS for row-layout rescale
        #pragma unroll
        for (int f = 0; f < 2; ++f)
            #pragma unroll
            for (int kk = 0; kk < 2; ++kk) {
                bf16x4 pk4;
                #pragma unroll
                for (int j = 0; j < 4; ++j) pk4[j] = f2b(s[f][kk][j]);
                *reinterpret_cast<bf16x4*>(&Pl[(size_t)(f * 16 + r) * 40 + kk * 16 + g * 4]) = pk4;
            }
        if (lane < 16) { sAl[r] = al0; sAl[16 + r] = al1; }
        asm volatile("s_waitcnt lgkmcnt(0)" ::: "memory");

        f32x4 ar0 = *reinterpret_cast<const f32x4*>(&sAl[g * 4]);
        f32x4 ar1 = *reinterpret_cast<const f32x4*>(&sAl[16 + g * 4]);
        bf16x8 pa0 = *reinterpret_cast<const bf16x8*>(&Pl[(size_t)r * 40 + g * 8]);
        bf16x8 pa1 = *reinterpret_cast<const bf16x8*>(&Pl[(size_t)(16 + r) * 40 + g * 8]);

        #pragma unroll
        for (int df = 0; df < 4; ++df) {
            #pragma unroll
            for (int j = 0; j < 4; ++j) { O[0][df][j] *= ar0[j]; O[1][df][j] *= ar1[j]; }
            O[0][df] = MFMA16(pa0, bv[df], O[0][df]);
            O[1][df] = MFMA16(pa1, bv[df], O[1][df]);
        }
    }

    // dump per-wave partials (reuse wave region as fp32 [32][64])
    float* sO = (float*)wreg[w];
    #pragma unroll
    for (int f = 0; f < 2; ++f)
        #pragma unroll
        for (int df = 0; df < 4; ++df)
            #pragma unroll
            for (int j = 0; j < 4; ++j)
                sO[(size_t)(f * 16 + g * 4 + j) * 64 + df * 16 + r] = O[f][df][j];
    if (lane < 16) {
        sm[w][r] = m0; sm[w][16 + r] = m1;
        sl[w][r] = l0; sl[w][16 + r] = l1;
    }
    __syncthreads();

    // combine 4 partials: thread -> (row, 8 cols)
    const int row = tid >> 3;          // 0..31
    const int c0  = (tid & 7) * 8;     // 0..56
    float mstar = fmaxf(fmaxf(sm[0][row], sm[1][row]), fmaxf(sm[2][row], sm[3][row]));
    float lstar = 0.f;
    f32x4 acc0 = {}, acc1 = {};
    #pragma unroll
    for (int w2 = 0; w2 < 4; ++w2) {
        float sc = __expf(sm[w2][row] - mstar);
        lstar += sl[w2][row] * sc;
        const float* po = (const float*)wreg[w2] + (size_t)row * 64 + c0;
        f32x4 o0 = *reinterpret_cast<const f32x4*>(po);
        f32x4 o1 = *reinterpret_cast<const f32x4*>(po + 4);
        #pragma unroll
        for (int c = 0; c < 4; ++c) { acc0[c] += o0[c] * sc; acc1[c] += o1[c] * sc; }
    }
    float inv = 1.f / lstar;
    bf16x8 pk;
    #pragma unroll
    for (int c = 0; c < 4; ++c) { pk[c] = f2b(acc0[c] * inv); pk[4 + c] = f2b(acc1[c] * inv); }
    *reinterpret_cast<bf16x8*>(Aout + ((size_t)b * NSEQ + qb + row) * CD + h * DH + c0) = pk;
}

// ------------------------------------------------------------------
// Output projection, LDS-staged: out = A @ Wo^T + bo.
// A [4096,512] bf16, Wo [512,512] fp32, out fp32. grid (64,8), block 256.
// ------------------------------------------------------------------
__global__ __launch_bounds__(256) void out_proj_kernel(
    const bf16_t* __restrict__ A, const float* __restrict__ Wo,
    const float* __restrict__ bo, float* __restrict__ Out)
{
    __shared__ bf16_t As[64][72];
    __shared__ bf16_t Ws[64][72];

    const int tid  = threadIdx.x;
    const int lane = tid & 63;
    const int wid  = tid >> 6;
    const int lrow = lane & 15;
    const int lk   = (lane >> 4) * 8;
    const int m0w  = (wid >> 1) * 32;
    const int n0w  = (wid & 1) * 32;
    const int bm   = blockIdx.x * 64;
    const int bn   = blockIdx.y * 64;

    const int srow = tid >> 4;
    const int sc4  = (tid & 15) * 4;

    f32x4 acc[2][2] = {};
    for (int k0 = 0; k0 < CD; k0 += 64) {
        #pragma unroll
        for (int rr = 0; rr < 4; ++rr) {
            int r = rr * 16 + srow;
            bf16x4 ab = *reinterpret_cast<const bf16x4*>(A + (size_t)(bm + r) * CD + k0 + sc4);
            f32x4  wv = *reinterpret_cast<const f32x4*>(Wo + (size_t)(bn + r) * CD + k0 + sc4);
            bf16x4 wb;
            #pragma unroll
            for (int c = 0; c < 4; ++c) wb[c] = f2b(wv[c]);
            *reinterpret_cast<bf16x4*>(&As[r][sc4]) = ab;
            *reinterpret_cast<bf16x4*>(&Ws[r][sc4]) = wb;
        }
        __syncthreads();
        #pragma unroll
        for (int kk = 0; kk < 2; ++kk) {
            int o = kk * 32 + lk;
            bf16x8 a0 = *reinterpret_cast<const bf16x8*>(&As[m0w + lrow][o]);
            bf16x8 a1 = *reinterpret_cast<const bf16x8*>(&As[m0w + 16 + lrow][o]);
            bf16x8 b0 = *reinterpret_cast<const bf16x8*>(&Ws[n0w + lrow][o]);
            bf16x8 b1 = *reinterpret_cast<const bf16x8*>(&Ws[n0w + 16 + lrow][o]);
            acc[0][0] = MFMA16(a0, b0, acc[0][0]);
            acc[0][1] = MFMA16(a0, b1, acc[0][1]);
            acc[1][0] = MFMA16(a1, b0, acc[1][0]);
            acc[1][1] = MFMA16(a1, b1, acc[1][1]);
        }
        __syncthreads();
    }

    #pragma unroll
    for (int f = 0; f < 2; ++f)
        #pragma unroll
        for (int g = 0; g < 2; ++g)
            #pragma unroll
            for (int j = 0; j < 4; ++j) {
                int row = bm + m0w + f * 16 + (lane >> 4) * 4 + j;
                int col = bn + n0w + g * 16 + lrow;
                Out[(size_t)row * CD + col] = acc[f][g][j] + bo[col];
            }
}

// simple d2d copy, 16 B per thread
__global__ __launch_bounds__(256) void copy16_kernel(
    const f32x4* __restrict__ src, f32x4* __restrict__ dst, int n16)
{
    int i = blockIdx.x * 256 + threadIdx.x;
    if (i < n16) dst[i] = src[i];
}

// ------------------------------------------------------------------
extern "C" void kernel_launch(void* const* d_in, const int* in_sizes, int n_in,
                              void* d_out, int out_size, void* d_ws, size_t ws_size,
                              hipStream_t stream)
{
    const float* q  = (const float*)d_in[0];
    const float* k  = (const float*)d_in[1];
    const float* v  = (const float*)d_in[2];
    const float* Wq = (const float*)d_in[3];
    const float* Wk = (const float*)d_in[4];
    const float* Wv = (const float*)d_in[5];
    const float* Wo = (const float*)d_in[6];
    const float* bo = (const float*)d_in[7];

    const size_t proj_elems = (size_t)MTOK * CD;        // 2,097,152 bf16 = 4 MB
    const size_t proj_bytes = proj_elems * sizeof(bf16_t);

    if (ws_size >= 4 * proj_bytes) {
        // --- Path A: everything fits in workspace (16 MB) ---
        bf16_t* Qp   = (bf16_t*)d_ws;
        bf16_t* Kp   = Qp + proj_elems;
        bf16_t* Vt   = Kp + proj_elems;
        bf16_t* Aout = Vt + proj_elems;

        qkv_proj_kernel<<<dim3(MTOK / 64, CD / 64, 3), 256, 0, stream>>>(
            q, k, v, Wq, Wk, Wv, Qp, Kp, Vt);
        attn_kernel<<<dim3(NB * NH, 64), 256, 0, stream>>>(Qp, Kp, Vt, Aout);
        out_proj_kernel<<<dim3(MTOK / 64, CD / 64), 256, 0, stream>>>(
            Aout, Wo, bo, (float*)d_out);
    } else {
        // --- Path B: ws has only ~8 MB; use d_out (8 MB fp32) as scratch ---
        bf16_t* Qp   = (bf16_t*)d_out;
        bf16_t* Kp   = (bf16_t*)d_ws;
        bf16_t* Vt   = Kp + proj_elems;
        bf16_t* Atmp = Qp + proj_elems;          // d_out bytes [4MB, 8MB)
        bf16_t* Afin = (bf16_t*)d_ws;            // reuse K region after attn

        qkv_proj_kernel<<<dim3(MTOK / 64, CD / 64, 3), 256, 0, stream>>>(
            q, k, v, Wq, Wk, Wv, Qp, Kp, Vt);
        attn_kernel<<<dim3(NB * NH, 64), 256, 0, stream>>>(Qp, Kp, Vt, Atmp);
        const int n16 = (int)(proj_bytes / 16);  // 262144
        copy16_kernel<<<dim3(n16 / 256), 256, 0, stream>>>(
            (const f32x4*)Atmp, (f32x4*)Afin, n16);
        out_proj_kernel<<<dim3(MTOK / 64, CD / 64), 256, 0, stream>>>(
            Afin, Wo, bo, (float*)d_out);
    }
}

// Round 8
// 69.843 us; speedup vs baseline: 2.8579x; 1.1064x over previous
//
#include <hip/hip_runtime.h>
#include <hip/hip_bf16.h>

typedef __bf16 bf16_t;
typedef __attribute__((ext_vector_type(4))) __bf16 bf16x4;
typedef __attribute__((ext_vector_type(8))) __bf16 bf16x8;
typedef __attribute__((ext_vector_type(4))) float f32x4;

#define MFMA16(a, b, c) __builtin_amdgcn_mfma_f32_16x16x32_bf16((a), (b), (c), 0, 0, 0)

constexpr int NB   = 2;      // batch
constexpr int NH   = 8;      // heads
constexpr int NSEQ = 2048;   // tokens
constexpr int CD   = 512;    // channel dim
constexpr int DH   = 64;     // head dim
constexpr int MTOK = NB * NSEQ;  // 4096

__device__ __forceinline__ bf16_t f2b(float x) { return (bf16_t)x; }

// ------------------------------------------------------------------
// QKV projection, LDS-staged + register prefetch: C = X @ W^T.
// Q,K out head-split bf16 [b][h][n][64]; V out TRANSPOSED [b][h][64][n].
// grid (64, 8, 3), block 256 (4 waves, 2x2 of 32x32 tiles).
// ------------------------------------------------------------------
__global__ __launch_bounds__(256) void qkv_proj_kernel(
    const float* __restrict__ Xq, const float* __restrict__ Xk, const float* __restrict__ Xv,
    const float* __restrict__ Wq, const float* __restrict__ Wk, const float* __restrict__ Wv,
    bf16_t* __restrict__ Qp, bf16_t* __restrict__ Kp, bf16_t* __restrict__ Vt)
{
    __shared__ bf16_t Xs[64][72];   // stride 36 words -> 2-way bank alias (free)
    __shared__ bf16_t Ws[64][72];

    const int z = blockIdx.z;
    const float* __restrict__ X = (z == 0) ? Xq : (z == 1) ? Xk : Xv;
    const float* __restrict__ W = (z == 0) ? Wq : (z == 1) ? Wk : Wv;
    bf16_t* __restrict__ Out    = (z == 0) ? Qp : (z == 1) ? Kp : Vt;

    const int tid  = threadIdx.x;
    const int lane = tid & 63;
    const int wid  = tid >> 6;
    const int lrow = lane & 15;
    const int lk   = (lane >> 4) * 8;
    const int m0w  = (wid >> 1) * 32;
    const int n0w  = (wid & 1) * 32;
    const int bm   = blockIdx.x * 64;
    const int bn   = blockIdx.y * 64;

    const int srow = tid >> 4;        // 0..15
    const int sc4  = (tid & 15) * 4;  // 0..60

    // prologue: load first K-step tiles into registers
    f32x4 xg[4], wg[4];
    #pragma unroll
    for (int rr = 0; rr < 4; ++rr) {
        int r = rr * 16 + srow;
        xg[rr] = *reinterpret_cast<const f32x4*>(X + (size_t)(bm + r) * CD + sc4);
        wg[rr] = *reinterpret_cast<const f32x4*>(W + (size_t)(bn + r) * CD + sc4);
    }

    f32x4 acc[2][2] = {};
    for (int k0 = 0; k0 < CD; k0 += 64) {
        #pragma unroll
        for (int rr = 0; rr < 4; ++rr) {
            int r = rr * 16 + srow;
            bf16x4 xb, wb;
            #pragma unroll
            for (int c = 0; c < 4; ++c) { xb[c] = f2b(xg[rr][c]); wb[c] = f2b(wg[rr][c]); }
            *reinterpret_cast<bf16x4*>(&Xs[r][sc4]) = xb;
            *reinterpret_cast<bf16x4*>(&Ws[r][sc4]) = wb;
        }
        __syncthreads();

        // prefetch next K-step (overlaps the MFMA block below)
        if (k0 + 64 < CD) {
            #pragma unroll
            for (int rr = 0; rr < 4; ++rr) {
                int r = rr * 16 + srow;
                xg[rr] = *reinterpret_cast<const f32x4*>(X + (size_t)(bm + r) * CD + k0 + 64 + sc4);
                wg[rr] = *reinterpret_cast<const f32x4*>(W + (size_t)(bn + r) * CD + k0 + 64 + sc4);
            }
        }

        #pragma unroll
        for (int kk = 0; kk < 2; ++kk) {
            int o = kk * 32 + lk;
            bf16x8 a0 = *reinterpret_cast<const bf16x8*>(&Xs[m0w + lrow][o]);
            bf16x8 a1 = *reinterpret_cast<const bf16x8*>(&Xs[m0w + 16 + lrow][o]);
            bf16x8 b0 = *reinterpret_cast<const bf16x8*>(&Ws[n0w + lrow][o]);
            bf16x8 b1 = *reinterpret_cast<const bf16x8*>(&Ws[n0w + 16 + lrow][o]);
            acc[0][0] = MFMA16(a0, b0, acc[0][0]);
            acc[0][1] = MFMA16(a0, b1, acc[0][1]);
            acc[1][0] = MFMA16(a1, b0, acc[1][0]);
            acc[1][1] = MFMA16(a1, b1, acc[1][1]);
        }
        __syncthreads();
    }

    if (z == 2) {
        // V transposed: Vt[((b*NH+h)*DH + d)*NSEQ + n], pack 4 consecutive n
        #pragma unroll
        for (int f = 0; f < 2; ++f)
            #pragma unroll
            for (int g = 0; g < 2; ++g) {
                int rowb = bm + m0w + f * 16 + (lane >> 4) * 4;  // 4-aligned
                int col  = bn + n0w + g * 16 + lrow;
                int b = rowb >> 11, n = rowb & (NSEQ - 1);
                int h = col >> 6,  d = col & (DH - 1);
                bf16x4 pk;
                #pragma unroll
                for (int j = 0; j < 4; ++j) pk[j] = f2b(acc[f][g][j]);
                *reinterpret_cast<bf16x4*>(Out + (((size_t)(b * NH + h) * DH) + d) * NSEQ + n) = pk;
            }
    } else {
        #pragma unroll
        for (int f = 0; f < 2; ++f)
            #pragma unroll
            for (int g = 0; g < 2; ++g)
                #pragma unroll
                for (int j = 0; j < 4; ++j) {
                    int row = bm + m0w + f * 16 + (lane >> 4) * 4 + j;
                    int col = bn + n0w + g * 16 + lrow;
                    int b = row >> 11, n = row & (NSEQ - 1);
                    int h = col >> 6,  d = col & (DH - 1);
                    Out[(((size_t)(b * NH + h) * NSEQ) + n) * DH + d] = f2b(acc[f][g][j]);
                }
    }
}

// ------------------------------------------------------------------
// Causal flash attention, split-KV x4, swapped QK^T, exp2-domain
// softmax, defer-max (THR=8 in log2), K double-buffer prefetch.
// grid (16 bh, 64 qblocks heavy-first), block 256.
// ------------------------------------------------------------------
__global__ __launch_bounds__(256) void attn_kernel(
    const bf16_t* __restrict__ Qp, const bf16_t* __restrict__ Kp,
    const bf16_t* __restrict__ Vt, bf16_t* __restrict__ Aout)
{
    // per-wave region: Pl[32][40] bf16 (2560 B) + sAl[32] f32 | sO[32][68] f32 (8704 B)
    __shared__ __align__(16) char wreg[4][8704];
    __shared__ float sm[4][32];
    __shared__ float sl[4][32];

    const int tid  = threadIdx.x;
    const int lane = tid & 63;
    const int w    = tid >> 6;
    const int r    = lane & 15;        // q-col (QK^T) / d-col (PV)
    const int g    = lane >> 4;        // 0..3
    const int bh = blockIdx.x;
    const int b = bh >> 3, h = bh & 7;
    const int p = 63 - blockIdx.y;     // heavy q-blocks first
    const int qb = p * 32;

    const bf16_t* Q = Qp + (size_t)bh * NSEQ * DH;
    const bf16_t* K = Kp + (size_t)bh * NSEQ * DH;
    const bf16_t* V = Vt + (size_t)bh * DH * NSEQ;

    bf16_t* Pl  = (bf16_t*)wreg[w];            // [32][40]
    float*  sAl = (float*)(wreg[w] + 2560);    // [32]

    // Q fragments, pre-scaled by (1/8)*log2(e)  -> softmax in exp2 domain
    const float QS = 0.125f * 1.4426950408889634f;
    bf16x8 qf[2][2];
    #pragma unroll
    for (int f = 0; f < 2; ++f)
        #pragma unroll
        for (int dh = 0; dh < 2; ++dh) {
            bf16x8 t = *reinterpret_cast<const bf16x8*>(
                Q + (size_t)(qb + f * 16 + r) * DH + dh * 32 + g * 8);
            #pragma unroll
            for (int i = 0; i < 8; ++i) qf[f][dh][i] = f2b((float)t[i] * QS);
        }

    float m0 = -1e30f, m1 = -1e30f, l0 = 0.f, l1 = 0.f;
    f32x4 O[2][4] = {};

    const bf16_t* Kl = K + (size_t)r * DH + g * 8;   // per-lane K base

    const int T = p + 1;
    bf16x8 kc[2][2];
    if (w < T) {
        const int kb0 = w * 32;
        #pragma unroll
        for (int kk = 0; kk < 2; ++kk) {
            kc[kk][0] = *reinterpret_cast<const bf16x8*>(Kl + (size_t)(kb0 + kk * 16) * DH);
            kc[kk][1] = *reinterpret_cast<const bf16x8*>(Kl + (size_t)(kb0 + kk * 16) * DH + 32);
        }
    }

    for (int t = w; t < T; t += 4) {
        const int kb = t * 32;

        // V fragments (consumed after softmax -> latency overlapped)
        bf16x8 bv[4];
        #pragma unroll
        for (int df = 0; df < 4; ++df)
            bv[df] = *reinterpret_cast<const bf16x8*>(V + (size_t)(df * 16 + r) * NSEQ + kb + g * 8);

        // prefetch next K-tile
        bf16x8 kn[2][2];
        const int tn = t + 4;
        if (tn < T) {
            const int kbn = tn * 32;
            #pragma unroll
            for (int kk = 0; kk < 2; ++kk) {
                kn[kk][0] = *reinterpret_cast<const bf16x8*>(Kl + (size_t)(kbn + kk * 16) * DH);
                kn[kk][1] = *reinterpret_cast<const bf16x8*>(Kl + (size_t)(kbn + kk * 16) * DH + 32);
            }
        }

        // swapped QK^T: s[f][kk][j] = S[k = kb+kk*16+4g+j][q = qb+f*16+r]
        f32x4 s[2][2] = {};
        #pragma unroll
        for (int kk = 0; kk < 2; ++kk)
            #pragma unroll
            for (int f = 0; f < 2; ++f) {
                s[f][kk] = MFMA16(kc[kk][0], qf[f][0], s[f][kk]);
                s[f][kk] = MFMA16(kc[kk][1], qf[f][1], s[f][kk]);
            }

        if (kb + 31 > qb) {   // only the diagonal tile masks
            #pragma unroll
            for (int f = 0; f < 2; ++f)
                #pragma unroll
                for (int kk = 0; kk < 2; ++kk)
                    #pragma unroll
                    for (int j = 0; j < 4; ++j) {
                        int kg = kb + kk * 16 + g * 4 + j;
                        int qg = qb + f * 16 + r;
                        if (kg > qg) s[f][kk][j] = -1e30f;
                    }
        }

        // row max: 7 in-reg fmax + 2 shfl per fragment
        float mx0 = fmaxf(fmaxf(fmaxf(s[0][0][0], s[0][0][1]), fmaxf(s[0][0][2], s[0][0][3])),
                          fmaxf(fmaxf(s[0][1][0], s[0][1][1]), fmaxf(s[0][1][2], s[0][1][3])));
        float mx1 = fmaxf(fmaxf(fmaxf(s[1][0][0], s[1][0][1]), fmaxf(s[1][0][2], s[1][0][3])),
                          fmaxf(fmaxf(s[1][1][0], s[1][1][1]), fmaxf(s[1][1][2], s[1][1][3])));
        mx0 = fmaxf(mx0, __shfl_xor(mx0, 16));
        mx1 = fmaxf(mx1, __shfl_xor(mx1, 16));
        mx0 = fmaxf(mx0, __shfl_xor(mx0, 32));
        mx1 = fmaxf(mx1, __shfl_xor(mx1, 32));

        // defer-max: only renormalize when max grew by > 8 (log2 domain)
        const bool renorm = __any((mx0 > m0 + 8.f) || (mx1 > m1 + 8.f));
        float al0 = 1.f, al1 = 1.f;
        if (renorm) {
            float mn0 = fmaxf(m0, mx0), mn1 = fmaxf(m1, mx1);
            al0 = exp2f(m0 - mn0); al1 = exp2f(m1 - mn1);
            m0 = mn0; m1 = mn1;
        }

        float rs0 = 0.f, rs1 = 0.f;
        #pragma unroll
        for (int kk = 0; kk < 2; ++kk)
            #pragma unroll
            for (int j = 0; j < 4; ++j) {
                float e0 = exp2f(s[0][kk][j] - m0);
                float e1 = exp2f(s[1][kk][j] - m1);
                s[0][kk][j] = e0; rs0 += e0;
                s[1][kk][j] = e1; rs1 += e1;
            }
        rs0 += __shfl_xor(rs0, 16);
        rs1 += __shfl_xor(rs1, 16);
        rs0 += __shfl_xor(rs0, 32);
        rs1 += __shfl_xor(rs1, 32);
        l0 = l0 * al0 + rs0;
        l1 = l1 * al1 + rs1;

        // P -> LDS (per-wave region); al -> LDS only when renormalizing
        #pragma unroll
        for (int f = 0; f < 2; ++f)
            #pragma unroll
            for (int kk = 0; kk < 2; ++kk) {
                bf16x4 pk4;
                #pragma unroll
                for (int j = 0; j < 4; ++j) pk4[j] = f2b(s[f][kk][j]);
                *reinterpret_cast<bf16x4*>(&Pl[(size_t)(f * 16 + r) * 40 + kk * 16 + g * 4]) = pk4;
            }
        if (renorm && lane < 16) { sAl[r] = al0; sAl[16 + r] = al1; }
        asm volatile("s_waitcnt lgkmcnt(0)" ::: "memory");

        bf16x8 pa0 = *reinterpret_cast<const bf16x8*>(&Pl[(size_t)r * 40 + g * 8]);
        bf16x8 pa1 = *reinterpret_cast<const bf16x8*>(&Pl[(size_t)(16 + r) * 40 + g * 8]);

        if (renorm) {
            f32x4 ar0 = *reinterpret_cast<const f32x4*>(&sAl[g * 4]);
            f32x4 ar1 = *reinterpret_cast<const f32x4*>(&sAl[16 + g * 4]);
            #pragma unroll
            for (int df = 0; df < 4; ++df)
                #pragma unroll
                for (int j = 0; j < 4; ++j) { O[0][df][j] *= ar0[j]; O[1][df][j] *= ar1[j]; }
        }

        #pragma unroll
        for (int df = 0; df < 4; ++df) {
            O[0][df] = MFMA16(pa0, bv[df], O[0][df]);
            O[1][df] = MFMA16(pa1, bv[df], O[1][df]);
        }

        // rotate K prefetch
        #pragma unroll
        for (int kk = 0; kk < 2; ++kk) { kc[kk][0] = kn[kk][0]; kc[kk][1] = kn[kk][1]; }
    }

    // dump per-wave partials (reuse wave region as fp32 [32][68])
    float* sO = (float*)wreg[w];
    #pragma unroll
    for (int f = 0; f < 2; ++f)
        #pragma unroll
        for (int df = 0; df < 4; ++df)
            #pragma unroll
            for (int j = 0; j < 4; ++j)
                sO[(size_t)(f * 16 + g * 4 + j) * 68 + df * 16 + r] = O[f][df][j];
    if (lane < 16) {
        sm[w][r] = m0; sm[w][16 + r] = m1;
        sl[w][r] = l0; sl[w][16 + r] = l1;
    }
    __syncthreads();

    // combine 4 partials: thread -> (row, 8 cols)
    const int row = tid >> 3;          // 0..31
    const int c0  = (tid & 7) * 8;     // 0..56
    float mstar = fmaxf(fmaxf(sm[0][row], sm[1][row]), fmaxf(sm[2][row], sm[3][row]));
    float lstar = 0.f;
    f32x4 acc0 = {}, acc1 = {};
    #pragma unroll
    for (int w2 = 0; w2 < 4; ++w2) {
        float sc = exp2f(sm[w2][row] - mstar);
        lstar += sl[w2][row] * sc;
        const float* po = (const float*)wreg[w2] + (size_t)row * 68 + c0;
        f32x4 o0 = *reinterpret_cast<const f32x4*>(po);
        f32x4 o1 = *reinterpret_cast<const f32x4*>(po + 4);
        #pragma unroll
        for (int c = 0; c < 4; ++c) { acc0[c] += o0[c] * sc; acc1[c] += o1[c] * sc; }
    }
    float inv = 1.f / lstar;
    bf16x8 pk;
    #pragma unroll
    for (int c = 0; c < 4; ++c) { pk[c] = f2b(acc0[c] * inv); pk[4 + c] = f2b(acc1[c] * inv); }
    *reinterpret_cast<bf16x8*>(Aout + ((size_t)b * NSEQ + qb + row) * CD + h * DH + c0) = pk;
}

// ------------------------------------------------------------------
// Output projection, LDS-staged + register prefetch: out = A @ Wo^T + bo.
// A [4096,512] bf16, Wo [512,512] fp32, out fp32. grid (64,8), block 256.
// ------------------------------------------------------------------
__global__ __launch_bounds__(256) void out_proj_kernel(
    const bf16_t* __restrict__ A, const float* __restrict__ Wo,
    const float* __restrict__ bo, float* __restrict__ Out)
{
    __shared__ bf16_t As[64][72];
    __shared__ bf16_t Ws[64][72];

    const int tid  = threadIdx.x;
    const int lane = tid & 63;
    const int wid  = tid >> 6;
    const int lrow = lane & 15;
    const int lk   = (lane >> 4) * 8;
    const int m0w  = (wid >> 1) * 32;
    const int n0w  = (wid & 1) * 32;
    const int bm   = blockIdx.x * 64;
    const int bn   = blockIdx.y * 64;

    const int srow = tid >> 4;
    const int sc4  = (tid & 15) * 4;

    bf16x4 ag[4];
    f32x4  wg[4];
    #pragma unroll
    for (int rr = 0; rr < 4; ++rr) {
        int r = rr * 16 + srow;
        ag[rr] = *reinterpret_cast<const bf16x4*>(A  + (size_t)(bm + r) * CD + sc4);
        wg[rr] = *reinterpret_cast<const f32x4*>(Wo + (size_t)(bn + r) * CD + sc4);
    }

    f32x4 acc[2][2] = {};
    for (int k0 = 0; k0 < CD; k0 += 64) {
        #pragma unroll
        for (int rr = 0; rr < 4; ++rr) {
            int r = rr * 16 + srow;
            bf16x4 wb;
            #pragma unroll
            for (int c = 0; c < 4; ++c) wb[c] = f2b(wg[rr][c]);
            *reinterpret_cast<bf16x4*>(&As[r][sc4]) = ag[rr];
            *reinterpret_cast<bf16x4*>(&Ws[r][sc4]) = wb;
        }
        __syncthreads();

        if (k0 + 64 < CD) {
            #pragma unroll
            for (int rr = 0; rr < 4; ++rr) {
                int r = rr * 16 + srow;
                ag[rr] = *reinterpret_cast<const bf16x4*>(A  + (size_t)(bm + r) * CD + k0 + 64 + sc4);
                wg[rr] = *reinterpret_cast<const f32x4*>(Wo + (size_t)(bn + r) * CD + k0 + 64 + sc4);
            }
        }

        #pragma unroll
        for (int kk = 0; kk < 2; ++kk) {
            int o = kk * 32 + lk;
            bf16x8 a0 = *reinterpret_cast<const bf16x8*>(&As[m0w + lrow][o]);
            bf16x8 a1 = *reinterpret_cast<const bf16x8*>(&As[m0w + 16 + lrow][o]);
            bf16x8 b0 = *reinterpret_cast<const bf16x8*>(&Ws[n0w + lrow][o]);
            bf16x8 b1 = *reinterpret_cast<const bf16x8*>(&Ws[n0w + 16 + lrow][o]);
            acc[0][0] = MFMA16(a0, b0, acc[0][0]);
            acc[0][1] = MFMA16(a0, b1, acc[0][1]);
            acc[1][0] = MFMA16(a1, b0, acc[1][0]);
            acc[1][1] = MFMA16(a1, b1, acc[1][1]);
        }
        __syncthreads();
    }

    #pragma unroll
    for (int f = 0; f < 2; ++f)
        #pragma unroll
        for (int g = 0; g < 2; ++g)
            #pragma unroll
            for (int j = 0; j < 4; ++j) {
                int row = bm + m0w + f * 16 + (lane >> 4) * 4 + j;
                int col = bn + n0w + g * 16 + lrow;
                Out[(size_t)row * CD + col] = acc[f][g][j] + bo[col];
            }
}

// simple d2d copy, 16 B per thread
__global__ __launch_bounds__(256) void copy16_kernel(
    const f32x4* __restrict__ src, f32x4* __restrict__ dst, int n16)
{
    int i = blockIdx.x * 256 + threadIdx.x;
    if (i < n16) dst[i] = src[i];
}

// ------------------------------------------------------------------
extern "C" void kernel_launch(void* const* d_in, const int* in_sizes, int n_in,
                              void* d_out, int out_size, void* d_ws, size_t ws_size,
                              hipStream_t stream)
{
    const float* q  = (const float*)d_in[0];
    const float* k  = (const float*)d_in[1];
    const float* v  = (const float*)d_in[2];
    const float* Wq = (const float*)d_in[3];
    const float* Wk = (const float*)d_in[4];
    const float* Wv = (const float*)d_in[5];
    const float* Wo = (const float*)d_in[6];
    const float* bo = (const float*)d_in[7];

    const size_t proj_elems = (size_t)MTOK * CD;        // 2,097,152 bf16 = 4 MB
    const size_t proj_bytes = proj_elems * sizeof(bf16_t);

    if (ws_size >= 4 * proj_bytes) {
        // --- Path A: everything fits in workspace (16 MB) ---
        bf16_t* Qp   = (bf16_t*)d_ws;
        bf16_t* Kp   = Qp + proj_elems;
        bf16_t* Vt   = Kp + proj_elems;
        bf16_t* Aout = Vt + proj_elems;

        qkv_proj_kernel<<<dim3(MTOK / 64, CD / 64, 3), 256, 0, stream>>>(
            q, k, v, Wq, Wk, Wv, Qp, Kp, Vt);
        attn_kernel<<<dim3(NB * NH, 64), 256, 0, stream>>>(Qp, Kp, Vt, Aout);
        out_proj_kernel<<<dim3(MTOK / 64, CD / 64), 256, 0, stream>>>(
            Aout, Wo, bo, (float*)d_out);
    } else {
        // --- Path B: ws has only ~8 MB; use d_out (8 MB fp32) as scratch ---
        bf16_t* Qp   = (bf16_t*)d_out;
        bf16_t* Kp   = (bf16_t*)d_ws;
        bf16_t* Vt   = Kp + proj_elems;
        bf16_t* Atmp = Qp + proj_elems;          // d_out bytes [4MB, 8MB)
        bf16_t* Afin = (bf16_t*)d_ws;            // reuse K region after attn

        qkv_proj_kernel<<<dim3(MTOK / 64, CD / 64, 3), 256, 0, stream>>>(
            q, k, v, Wq, Wk, Wv, Qp, Kp, Vt);
        attn_kernel<<<dim3(NB * NH, 64), 256, 0, stream>>>(Qp, Kp, Vt, Atmp);
        const int n16 = (int)(proj_bytes / 16);  // 262144
        copy16_kernel<<<dim3(n16 / 256), 256, 0, stream>>>(
            (const f32x4*)Atmp, (f32x4*)Afin, n16);
        out_proj_kernel<<<dim3(MTOK / 64, CD / 64), 256, 0, stream>>>(
            Afin, Wo, bo, (float*)d_out);
    }
}